// Round 6
// baseline (912.006 us; speedup 1.0000x reference)
//
#include <hip/hip_runtime.h>
#include <hip/hip_bf16.h>
#include <cstdint>
#include <cstddef>

constexpr int Nn = 4096;
constexpr int NB = 64;        // value buckets for leaky-relu threshold
constexpr int MC = 3 * NB;    // M columns per head: indicator | f1hi | f1lo
constexpr int TW = 132;       // table row width: C0x[65] C1x[65] mx' pad

typedef __attribute__((ext_vector_type(8))) short bf16x8;
typedef __attribute__((ext_vector_type(8))) short short8;
typedef __attribute__((ext_vector_type(4))) float f32x4;

__device__ __forceinline__ unsigned short f2bf(float x) {
  union { float f; unsigned u; } v; v.f = x;
  unsigned r = v.u + 0x7FFFu + ((v.u >> 16) & 1u);
  return (unsigned short)(r >> 16);
}
__device__ __forceinline__ float bf2f(unsigned short b) {
  union { unsigned u; float f; } v; v.u = ((unsigned)b) << 16; return v.f;
}

// f32 -> bf16, 8 elems/thread
__global__ __launch_bounds__(256) void k_cvt(
    const float* __restrict__ in, unsigned short* __restrict__ out) {
  size_t id = ((size_t)blockIdx.x * 256 + threadIdx.x) * 8;
  const float4 a = *(const float4*)(in + id);
  const float4 b = *(const float4*)(in + id + 4);
  short8 v;
  v[0] = (short)f2bf(a.x); v[1] = (short)f2bf(a.y);
  v[2] = (short)f2bf(a.z); v[3] = (short)f2bf(a.w);
  v[4] = (short)f2bf(b.x); v[5] = (short)f2bf(b.y);
  v[6] = (short)f2bf(b.z); v[7] = (short)f2bf(b.w);
  *(short8*)(out + id) = v;
}

// h = prev[N,din] @ W[din,64]; writes htr (bf16 transposed [64][N]),
// f1 = h@av[:64], f2 = h@av[64:]. One wave per row, lane == out dim.
__global__ __launch_bounds__(256) void k_hf4(
    const float* __restrict__ prev, int din,
    const float* __restrict__ Wb, size_t wstride,
    const float* __restrict__ avb, size_t avstride,
    unsigned short* __restrict__ htrb,
    float* __restrict__ f1b, float* __restrict__ f2b) {
  __shared__ float Wl[64 * 64];
  int h = blockIdx.y;
  const float* W  = Wb + (size_t)h * wstride;
  const float* av = avb + (size_t)h * avstride;
  unsigned short* htr = htrb + (size_t)h * 64 * Nn;
  int t = threadIdx.x;
  int r = __builtin_amdgcn_readfirstlane(blockIdx.x * 4 + (t >> 6));
  int d = t & 63;
  const float* pr = prev + (size_t)r * din;
  float acc = 0.f;
  for (int kb = 0; kb < din; kb += 64) {
    for (int i = t; i < 64 * 64; i += 256) Wl[i] = W[kb * 64 + i];
    __syncthreads();
    #pragma unroll 8
    for (int k = 0; k < 64; ++k) acc = fmaf(pr[kb + k], Wl[k * 64 + d], acc);
    __syncthreads();
  }
  htr[(size_t)d * Nn + r] = f2bf(acc);
  float p1 = acc * av[d];
  float p2 = acc * av[64 + d];
  #pragma unroll
  for (int off = 32; off; off >>= 1) {
    p1 += __shfl_down(p1, off);
    p2 += __shfl_down(p2, off);
  }
  if (d == 0) { f1b[h * Nn + r] = p1; f2b[h * Nn + r] = p2; }
}

// Build M (bf16, [h][MC][Nn]) densely + jb[j] thresholds. grid (MC, nh).
__global__ __launch_bounds__(256) void k_mbuild(
    const float* __restrict__ f1b, const float* __restrict__ f2b,
    unsigned short* __restrict__ Mb, unsigned char* __restrict__ jbb) {
  __shared__ float fl[Nn];
  __shared__ float red[16];
  int h = blockIdx.y, col = blockIdx.x;
  const float* f1 = f1b + (size_t)h * Nn;
  int t = threadIdx.x, lane = t & 63, wv = t >> 6;
  float lmin = 3e38f, lmax = -3e38f;
  #pragma unroll
  for (int i = 0; i < 16; ++i) {
    float v = f1[i * 256 + t];
    fl[i * 256 + t] = v;
    lmin = fminf(lmin, v); lmax = fmaxf(lmax, v);
  }
  #pragma unroll
  for (int off = 32; off; off >>= 1) {
    lmin = fminf(lmin, __shfl_xor(lmin, off));
    lmax = fmaxf(lmax, __shfl_xor(lmax, off));
  }
  if (lane == 0) { red[wv] = lmin; red[8 + wv] = lmax; }
  __syncthreads();
  float emin = fminf(fminf(red[0], red[1]), fminf(red[2], red[3]));
  float emax = fmaxf(fmaxf(red[8], red[9]), fmaxf(red[10], red[11]));
  float wr = emax - emin;
  float invw = (wr > 0.f) ? (float)NB / wr : 0.f;
  int part = col >> 6, bb = col & 63;
  unsigned short* mrow = Mb + ((size_t)h * MC + col) * Nn;
  #pragma unroll
  for (int i = 0; i < 16; ++i) {
    int k = i * 256 + t;
    float f = fl[k];
    int b = (int)floorf((emax - f) * invw);
    b = b < 0 ? 0 : (b > NB - 1 ? NB - 1 : b);
    unsigned short val = 0;
    if (b == bb) {
      if (part == 0) val = 0x3F80;   // bf16(1.0)
      else {
        unsigned short hb = f2bf(f);
        val = (part == 1) ? hb : f2bf(f - bf2f(hb));
      }
    }
    mrow[k] = val;
  }
  if (col == 0) {
    const float* f2 = f2b + (size_t)h * Nn;
    #pragma unroll
    for (int i = 0; i < 16; ++i) {
      int j = i * 256 + t;
      int b = (int)floorf((emax + f2[j]) * invw + 0.5f);
      b = b < 0 ? 0 : (b > NB ? NB : b);
      jbb[(size_t)h * Nn + j] = (unsigned char)b;
    }
  }
}

// LDS-staged tile GEMM. C[4096, ldc-wide] += A[4096,4096] @ B^T-slice.
// AMODE 0: A bf16; 2: A f32 split hi/lo. BSPLIT: B hi/lo planes.
// Tile BM=128 x NCB, BK=64, 4 waves (32 rows each).
// grid (Nn/128, SK*CG, nh). Cpart per head: [SK][Nn][ldc], col off cg*NCB.
template<int AMODE, int NCB, bool BSPLIT>
__global__ __launch_bounds__(256) void k_gemm(
    const void* __restrict__ Ap, size_t astride,
    const unsigned short* __restrict__ Bthb,
    const unsigned short* __restrict__ Btlb, size_t bstride,
    float* __restrict__ Cpartb, size_t cstride, int ldc, int CG) {
  constexpr int APL = (AMODE == 2) ? 2 : 1;
  constexpr int BPL = BSPLIT ? 2 : 1;
  constexpr int NT = NCB / 16;
  __shared__ __align__(16) unsigned short Abuf[APL][128][72];
  __shared__ __align__(16) unsigned short Bbuf[BPL][NCB][72];
  int h = blockIdx.z;
  int cg = blockIdx.y % CG;
  int kc = blockIdx.y / CG;
  int SK = gridDim.y / CG;
  int kslice = Nn / SK;
  const unsigned short* Bth = Bthb + (size_t)h * bstride + (size_t)(cg * NCB) * Nn;
  const unsigned short* Btl = BSPLIT
      ? (Btlb + (size_t)h * bstride + (size_t)(cg * NCB) * Nn) : nullptr;
  float* Cpart = Cpartb + (size_t)h * cstride + (size_t)kc * Nn * ldc + cg * NCB;
  int t = threadIdx.x;
  int wv = t >> 6, l = t & 63;
  int l15 = l & 15, lq = l >> 4;
  int row0 = blockIdx.x * 128;
  f32x4 acc[2][NT] = {};
  for (int kt = kc * kslice; kt < (kc + 1) * kslice; kt += 64) {
    __syncthreads();
    #pragma unroll
    for (int i = 0; i < 4; ++i) {
      int cid = i * 256 + t;
      int row = cid >> 3, ch = cid & 7;
      if constexpr (AMODE == 0) {
        bf16x8 v = *(const bf16x8*)((const unsigned short*)Ap +
                     (size_t)h * astride + (size_t)(row0 + row) * Nn + kt + ch * 8);
        *(bf16x8*)&Abuf[0][row][ch * 8] = v;
      } else {
        const float* fp = (const float*)Ap + (size_t)(row0 + row) * Nn + kt + ch * 8;
        const float4 xa = *(const float4*)fp;
        const float4 xb = *(const float4*)(fp + 4);
        float xs[8] = {xa.x, xa.y, xa.z, xa.w, xb.x, xb.y, xb.z, xb.w};
        bf16x8 hi, lo;
        #pragma unroll
        for (int e = 0; e < 8; ++e) {
          unsigned short hb = f2bf(xs[e]);
          hi[e] = (short)hb;
          lo[e] = (short)f2bf(xs[e] - bf2f(hb));
        }
        *(bf16x8*)&Abuf[0][row][ch * 8] = hi;
        *(bf16x8*)&Abuf[APL - 1][row][ch * 8] = lo;
      }
    }
    #pragma unroll
    for (int i = 0; i < NCB / 32; ++i) {
      int cid = i * 256 + t;
      int row = cid >> 3, ch = cid & 7;
      bf16x8 v = *(const bf16x8*)(Bth + (size_t)row * Nn + kt + ch * 8);
      *(bf16x8*)&Bbuf[0][row][ch * 8] = v;
      if constexpr (BSPLIT) {
        bf16x8 w = *(const bf16x8*)(Btl + (size_t)row * Nn + kt + ch * 8);
        *(bf16x8*)&Bbuf[BPL - 1][row][ch * 8] = w;
      }
    }
    __syncthreads();
    #pragma unroll
    for (int k0 = 0; k0 < 64; k0 += 32) {
      bf16x8 a0 = *(const bf16x8*)&Abuf[0][wv * 32 + l15][k0 + lq * 8];
      bf16x8 a1 = *(const bf16x8*)&Abuf[0][wv * 32 + 16 + l15][k0 + lq * 8];
      bf16x8 a0l, a1l;
      if constexpr (AMODE == 2) {
        a0l = *(const bf16x8*)&Abuf[APL - 1][wv * 32 + l15][k0 + lq * 8];
        a1l = *(const bf16x8*)&Abuf[APL - 1][wv * 32 + 16 + l15][k0 + lq * 8];
      }
      #pragma unroll
      for (int ct = 0; ct < NT; ++ct) {
        bf16x8 bh = *(const bf16x8*)&Bbuf[0][ct * 16 + l15][k0 + lq * 8];
        acc[0][ct] = __builtin_amdgcn_mfma_f32_16x16x32_bf16(a0, bh, acc[0][ct], 0, 0, 0);
        acc[1][ct] = __builtin_amdgcn_mfma_f32_16x16x32_bf16(a1, bh, acc[1][ct], 0, 0, 0);
        if constexpr (BSPLIT) {
          bf16x8 bl = *(const bf16x8*)&Bbuf[BPL - 1][ct * 16 + l15][k0 + lq * 8];
          acc[0][ct] = __builtin_amdgcn_mfma_f32_16x16x32_bf16(a0, bl, acc[0][ct], 0, 0, 0);
          acc[1][ct] = __builtin_amdgcn_mfma_f32_16x16x32_bf16(a1, bl, acc[1][ct], 0, 0, 0);
        }
        if constexpr (AMODE == 2) {
          acc[0][ct] = __builtin_amdgcn_mfma_f32_16x16x32_bf16(a0l, bh, acc[0][ct], 0, 0, 0);
          acc[1][ct] = __builtin_amdgcn_mfma_f32_16x16x32_bf16(a1l, bh, acc[1][ct], 0, 0, 0);
        }
      }
    }
  }
  // D layout (m89-verified): col = lane&15, row = 4*(lane>>4)+reg
  #pragma unroll
  for (int mi = 0; mi < 2; ++mi) {
    #pragma unroll
    for (int ct = 0; ct < NT; ++ct) {
      #pragma unroll
      for (int q = 0; q < 4; ++q) {
        int r = row0 + wv * 32 + mi * 16 + lq * 4 + q;
        Cpart[(size_t)r * ldc + ct * 16 + l15] = acc[mi][ct][q];
      }
    }
  }
}

// Per row r, per head: sum SK hist parts, prefix scan, full s-pass for
// mx/sum, write per-row table [C0x[65] | C1x[65] | mx+ln(sum)].
template<int SK>
__global__ __launch_bounds__(256) void k_tab(
    const float* __restrict__ Hb, const float* __restrict__ f2b,
    const unsigned char* __restrict__ jbb, float* __restrict__ tabs,
    size_t tstride, int nh) {
  __shared__ float hr[MC];
  __shared__ float C0x[NB + 1], C1x[NB + 1];
  __shared__ float red[8];
  int t = threadIdx.x;
  int lane = t & 63, wv = t >> 6;
  int r = blockIdx.x;
  for (int h = 0; h < nh; ++h) {
    if (h) __syncthreads();
    if (t < MC) {
      const float* p = Hb + (size_t)h * SK * Nn * MC + (size_t)r * MC + t;
      float s = 0.f;
      #pragma unroll
      for (int sk = 0; sk < SK; ++sk) s += p[(size_t)sk * Nn * MC];
      hr[t] = s;
    }
    __syncthreads();
    if (t < 64) {
      float v0 = hr[t];
      float v1 = hr[64 + t] + hr[128 + t];
      #pragma unroll
      for (int off = 1; off < 64; off <<= 1) {
        float u0 = __shfl_up(v0, off);
        float u1 = __shfl_up(v1, off);
        if (lane >= off) { v0 += u0; v1 += u1; }
      }
      C0x[t + 1] = v0; C1x[t + 1] = v1;
      if (t == 0) { C0x[0] = 0.f; C1x[0] = 0.f; }
    }
    __syncthreads();
    float S0 = C0x[NB], S1 = C1x[NB];
    const float* f2 = f2b + (size_t)h * Nn;
    const unsigned char* jb = jbb + (size_t)h * Nn;
    float sv[16];
    float mx = -3.0e38f;
    #pragma unroll
    for (int c = 0; c < 16; ++c) {
      int j = c * 256 + t;
      float fj = f2[j];
      int b = jb[j];
      float s = 0.2f * fmaf(fj, S0, S1) + 0.8f * fmaf(fj, C0x[b], C1x[b]);
      sv[c] = s;
      mx = fmaxf(mx, s);
    }
    #pragma unroll
    for (int off = 32; off; off >>= 1) mx = fmaxf(mx, __shfl_xor(mx, off));
    __syncthreads();
    if (lane == 0) red[wv] = mx;
    __syncthreads();
    mx = fmaxf(fmaxf(red[0], red[1]), fmaxf(red[2], red[3]));
    float sum = 0.f;
    #pragma unroll
    for (int c = 0; c < 16; ++c) sum += __expf(sv[c] - mx);
    #pragma unroll
    for (int off = 32; off; off >>= 1) sum += __shfl_xor(sum, off);
    __syncthreads();
    if (lane == 0) red[4 + wv] = sum;
    __syncthreads();
    float mxp = mx + __logf(red[4] + red[5] + red[6] + red[7]);
    float* tr = tabs + (size_t)h * tstride + (size_t)r * TW;
    if (t < 65) tr[t] = C0x[t];
    else if (t < 130) tr[t] = C1x[t - 65];
    else if (t == 130) tr[130] = mxp;
  }
}

// Fused softmax+PV GEMM: C[r,d] = sum_j exp(s(r,j)-mx') * h[j,d].
// att regenerated in-register from per-row tables (LDS, loaded once).
// BM=64, 4 waves x 16 rows; B read direct from L2 (htr). No K-loop barriers.
template<int DN>
__global__ __launch_bounds__(256) void k_pv(
    const float* __restrict__ tabs, size_t tstride,
    const float* __restrict__ f2b, const unsigned char* __restrict__ jbb,
    const unsigned short* __restrict__ htrb, size_t bstride,
    float* __restrict__ cpartb, size_t cstride) {
  __shared__ float Tf[64 * TW];   // 33.8KB
  int h = blockIdx.z;
  int kc = blockIdx.y;
  int kslice = Nn / gridDim.y;
  int row0 = blockIdx.x * 64;
  const float* tab = tabs + (size_t)h * tstride + (size_t)row0 * TW;
  int t = threadIdx.x;
  for (int i = t; i < 64 * TW / 4; i += 256)
    ((float4*)Tf)[i] = ((const float4*)tab)[i];
  __syncthreads();
  int wv = t >> 6, l = t & 63, l15 = l & 15, lq = l >> 4;
  const float* Tr = Tf + (wv * 16 + l15) * TW;
  float S0 = Tr[64], S1 = Tr[129], mxp = Tr[130];
  const float* f2 = f2b + (size_t)h * Nn;
  const unsigned char* jb = jbb + (size_t)h * Nn;
  const unsigned short* htr = htrb + (size_t)h * bstride;
  f32x4 acc[DN / 16] = {};
  for (int jt = kc * kslice; jt < (kc + 1) * kslice; jt += 32) {
    int j0 = jt + lq * 8;
    const float4 fa = *(const float4*)(f2 + j0);
    const float4 fb = *(const float4*)(f2 + j0 + 4);
    const uint2 jraw = *(const uint2*)(jb + j0);
    float fjs[8] = {fa.x, fa.y, fa.z, fa.w, fb.x, fb.y, fb.z, fb.w};
    bf16x8 af;
    #pragma unroll
    for (int e = 0; e < 8; ++e) {
      unsigned bword = (e < 4) ? jraw.x : jraw.y;
      int b = (bword >> (8 * (e & 3))) & 255;
      float fj = fjs[e];
      float s = 0.2f * fmaf(fj, S0, S1) + 0.8f * fmaf(fj, Tr[b], Tr[65 + b]);
      af[e] = (short)f2bf(__expf(s - mxp));
    }
    #pragma unroll
    for (int ct = 0; ct < DN / 16; ++ct) {
      bf16x8 bh = *(const bf16x8*)(htr + (size_t)(ct * 16 + l15) * Nn + j0);
      acc[ct] = __builtin_amdgcn_mfma_f32_16x16x32_bf16(af, bh, acc[ct], 0, 0, 0);
    }
  }
  float* Cpart = cpartb + (size_t)h * cstride + (size_t)kc * Nn * DN;
  #pragma unroll
  for (int ct = 0; ct < DN / 16; ++ct) {
    #pragma unroll
    for (int q = 0; q < 4; ++q) {
      int r = row0 + wv * 16 + lq * 4 + q;
      Cpart[(size_t)r * DN + ct * 16 + l15] = acc[ct][q];
    }
  }
}

// sum split-K partials + epilogue (0 none, 1 elu, 2 relu); optional strided
// f32 write and/or transposed bf16 hi/lo planes. Batched over blockIdx.y.
template<int NC, int SK>
__global__ __launch_bounds__(256) void k_red4(
    const float* __restrict__ Cpartb, size_t cph,
    float* __restrict__ dst, int ldd, int coff0, int coffstep, int epi,
    unsigned short* __restrict__ oh, unsigned short* __restrict__ ol) {
  int h = blockIdx.y;
  const float* cp = Cpartb + (size_t)h * cph;
  int id = blockIdx.x * 256 + threadIdx.x;
  int r = id / NC, c = id % NC;
  float s = 0.f;
  #pragma unroll
  for (int kc = 0; kc < SK; ++kc) s += cp[((size_t)kc * Nn + r) * NC + c];
  if (epi == 1) s = (s > 0.f) ? s : expm1f(s);
  else if (epi == 2) s = fmaxf(s, 0.f);
  if (dst) dst[(size_t)r * ldd + coff0 + h * coffstep + c] = s;
  if (oh) {
    unsigned short hb = f2bf(s);
    oh[(size_t)c * Nn + r] = hb;
    if (ol) ol[(size_t)c * Nn + r] = f2bf(s - bf2f(hb));
  }
}

// fused: h1 = relu(sum of 32 partials); u = h1 @ l2w[64,32]; ut bf16 [32][N]
__global__ __launch_bounds__(256) void k_redU(
    const float* __restrict__ Cpart, const float* __restrict__ W,
    unsigned short* __restrict__ ut) {
  __shared__ float hl[4][64];
  __shared__ float Wl[64 * 32];
  int t = threadIdx.x;
  for (int i = t; i < 64 * 32; i += 256) Wl[i] = W[i];
  int id = blockIdx.x * 256 + t;
  int r = id >> 6, c = id & 63;
  float s = 0.f;
  #pragma unroll
  for (int kc = 0; kc < 32; ++kc) s += Cpart[((size_t)kc * Nn + r) * 64 + c];
  hl[t >> 6][c] = fmaxf(s, 0.f);
  __syncthreads();
  if (t < 128) {
    int lr = t >> 5, d = t & 31;
    int row = blockIdx.x * 4 + lr;
    const float* hrr = hl[lr];
    float acc = 0.f;
    #pragma unroll 8
    for (int k = 0; k < 64; ++k) acc = fmaf(hrr[k], Wl[k * 32 + d], acc);
    ut[(size_t)d * Nn + row] = f2bf(acc);
  }
}

extern "C" void kernel_launch(void* const* d_in, const int* in_sizes, int n_in,
                              void* d_out, int out_size, void* d_ws, size_t ws_size,
                              hipStream_t stream) {
  (void)in_sizes; (void)n_in; (void)out_size; (void)ws_size;
  const float* x    = (const float*)d_in[0];
  const float* adj  = (const float*)d_in[1];
  const float* wini = (const float*)d_in[2];
  const float* hH   = (const float*)d_in[3];
  const float* ha   = (const float*)d_in[4];
  const float* oH   = (const float*)d_in[5];
  const float* oa   = (const float*)d_in[6];
  const float* l2w  = (const float*)d_in[7];

  char* ws = (char*)d_ws;
  size_t off = 0;
  auto alloc = [&](size_t bytes) -> void* {
    void* p = ws + off;
    off += (bytes + 4095) & ~(size_t)4095;
    return p;
  };
  unsigned short* adjbf = (unsigned short*)alloc((size_t)Nn * Nn * 2);        // 32MB
  unsigned short* htr4  = (unsigned short*)alloc((size_t)4 * 64 * Nn * 2);    // 2MB
  float* f14            = (float*)alloc((size_t)4 * Nn * 4);
  float* f24            = (float*)alloc((size_t)4 * Nn * 4);
  unsigned char* jb4    = (unsigned char*)alloc((size_t)4 * Nn);
  unsigned short* Mbuf  = (unsigned short*)alloc((size_t)4 * MC * Nn * 2);    // 6MB
  float* Hbuf           = (float*)alloc((size_t)4 * 4 * Nn * MC * 4);         // 50MB
  float* tabs           = (float*)alloc((size_t)4 * Nn * TW * 4);             // 8.6MB
  float* cpart          = (float*)alloc((size_t)32 * Nn * 64 * 4);            // 32MB
  float* cat            = (float*)alloc((size_t)Nn * 256 * 4);                // 4MB
  float* x1             = (float*)alloc((size_t)Nn * 64 * 4);
  unsigned short* bth   = (unsigned short*)alloc((size_t)Nn * 64 * 2);
  unsigned short* btl   = (unsigned short*)alloc((size_t)Nn * 64 * 2);

  const size_t BS  = (size_t)64 * Nn;        // htr stride per head (ushort)
  const size_t MS  = (size_t)MC * Nn;        // M stride per head (ushort)
  const size_t HS4 = (size_t)4 * Nn * MC;    // Hbuf per-head stride (SK=4)
  const size_t TS  = (size_t)Nn * TW;        // tabs per-head stride (f32)
  const size_t CS8 = (size_t)8 * Nn * 64;    // cpart per-head stride (SK=8)

  auto run_stage = [&](const float* xin, int din, const float* Hm, size_t hms,
                       const float* av, size_t avs, int nh) {
    k_hf4<<<dim3(Nn / 4, nh), 256, 0, stream>>>(xin, din, Hm, hms, av, avs,
                                                htr4, f14, f24);
    k_mbuild<<<dim3(MC, nh), 256, 0, stream>>>(f14, f24, Mbuf, jb4);
    if (nh == 4) {
      // hist: NCB=192, CG=1, SK=4 -> 512 blocks; A read once per head
      k_gemm<0, 192, false><<<dim3(32, 4, 4), 256, 0, stream>>>(
          adjbf, 0, Mbuf, nullptr, MS, Hbuf, HS4, MC, 1);
      k_tab<4><<<dim3(Nn), 256, 0, stream>>>(Hbuf, f24, jb4, tabs, TS, 4);
      k_pv<64><<<dim3(64, 8, 4), 256, 0, stream>>>(
          tabs, TS, f24, jb4, htr4, BS, cpart, CS8);
      k_red4<64, 8><<<dim3(Nn * 64 / 256, 4), 256, 0, stream>>>(
          cpart, CS8, cat, 256, 0, 64, 1, nullptr, nullptr);
    } else {
      // hist: NCB=96, CG=2, SK=8 -> 512 blocks
      k_gemm<0, 96, false><<<dim3(32, 16, 1), 256, 0, stream>>>(
          adjbf, 0, Mbuf, nullptr, 0, Hbuf, 0, MC, 2);
      k_tab<8><<<dim3(Nn), 256, 0, stream>>>(Hbuf, f24, jb4, tabs, TS, 1);
      k_pv<64><<<dim3(64, 16, 1), 256, 0, stream>>>(
          tabs, TS, f24, jb4, htr4, 0, cpart, 0);
    }
  };

  const float* prev = wini;
  for (int cell = 0; cell < 2; ++cell) {
    const float* adj_c = adj + (size_t)cell * Nn * Nn;
    k_cvt<<<dim3(Nn * Nn / 8 / 256), 256, 0, stream>>>(adj_c, adjbf);
    run_stage(prev, 64, hH + (size_t)cell * 4 * 64 * 64, (size_t)64 * 64,
              ha + (size_t)cell * 4 * 128, 128, 4);
    run_stage(cat, 256, oH + (size_t)cell * 256 * 64, 0,
              oa + (size_t)cell * 128, 0, 1);
    if (cell == 0)
      k_red4<64, 16><<<dim3(Nn * 64 / 256, 1), 256, 0, stream>>>(
          cpart, 0, x1, 64, 0, 0, 1, nullptr, nullptr);
    else
      k_red4<64, 16><<<dim3(Nn * 64 / 256, 1), 256, 0, stream>>>(
          cpart, 0, nullptr, 0, 0, 0, 1, bth, btl);
    prev = x1;
  }

  // tail (cell 1 only; adjbf holds cell-1 adj in bf16)
  const float* x1c = x + (size_t)Nn * Nn;
  // t0 = x @ elu(x1)
  k_gemm<2, 64, true><<<dim3(32, 32, 1), 256, 0, stream>>>(
      x1c, 0, bth, btl, 0, cpart, 0, 64, 1);
  k_red4<64, 32><<<dim3(Nn * 64 / 256, 1), 256, 0, stream>>>(
      cpart, 0, nullptr, 0, 0, 0, 0, bth, nullptr);        // t0 -> bth
  // h1 = relu(adj1 @ t0); u = h1 @ l2w
  k_gemm<0, 64, false><<<dim3(32, 32, 1), 256, 0, stream>>>(
      adjbf, 0, bth, nullptr, 0, cpart, 0, 64, 1);
  k_redU<<<dim3(Nn / 4), 256, 0, stream>>>(
      cpart, l2w + 64 * 32, bth);                          // u -> bth[32][N]
  // h2 = adj1 @ u
  k_gemm<0, 32, false><<<dim3(32, 32, 1), 256, 0, stream>>>(
      adjbf, 0, bth, nullptr, 0, cpart, 0, 32, 1);
  k_red4<32, 32><<<dim3(Nn * 32 / 256, 1), 256, 0, stream>>>(
      cpart, 0, (float*)d_out, 32, 0, 0, 0, nullptr, nullptr);
}